// Round 2
// baseline (339.742 us; speedup 1.0000x reference)
//
#include <hip/hip_runtime.h>

// QPChargeNormalization v3: per batch row b (n = 8192 = 4096 iso + 4096 aniso):
//   h = u/2 = (sum(charge[b]) - q.c) / (q.q);  x = c + h*q
//
// Structure: ONE ROW PER WAVE, two streaming passes over the row.
//   pass 1: dot-products with accumulators only (no payload retention)
//   wave-local __shfl_xor butterfly reduce (no __syncthreads, no LDS)
//   pass 2: re-read c,q and store x. The re-read hits L2/L3: the row
//           (64 KiB) was fetched by this same wave moments earlier, and
//           total concurrent-row footprint is bounded at
//           2048 waves x 64 KiB = 128 MiB <= 256 MiB Infinity Cache.
// This removes the v1/v2 bottleneck: register-resident payload forced
// vmcnt(0) serialization of the whole load stream against a block-wide
// barrier + reduce. Here waves are fully independent streams.
// Plain stores (non-temporal stores measured +25% write amplification).

#define HALF_N 4096   // floats per row in each of the iso/aniso halves
#define BLOCK  256
#define WPB    4      // waves per block
#define RPW    2      // rows per wave  -> grid = B / (WPB*RPW) = 512 blocks

typedef float f4 __attribute__((ext_vector_type(4)));

__global__ __launch_bounds__(BLOCK, 4) void qp_charge_norm_kernel(
    const float* __restrict__ c_iso,
    const float* __restrict__ c_aniso,
    const float* __restrict__ q_iso,
    const float* __restrict__ q_aniso,
    const float* __restrict__ charge,   // [B, 256]
    float* __restrict__ out,            // [B*4096 iso][B*4096 aniso]
    int B)
{
    const int wave  = threadIdx.x >> 6;
    const int lane  = threadIdx.x & 63;
    const int gwave = blockIdx.x * WPB + wave;

    for (int i = 0; i < RPW; ++i) {
        const int b = gwave * RPW + i;
        if (b >= B) return;

        const f4* ci = (const f4*)(c_iso   + (size_t)b * HALF_N);
        const f4* ca = (const f4*)(c_aniso + (size_t)b * HALF_N);
        const f4* qi = (const f4*)(q_iso   + (size_t)b * HALF_N);
        const f4* qa = (const f4*)(q_aniso + (size_t)b * HALF_N);

        // charge row: 256 floats = one f4 per lane, coalesced 1 KiB
        f4 ch = ((const f4*)(charge + (size_t)b * 256))[lane];

        // ---- pass 1: streaming dot products (16 f4 per lane per half) ----
        float qc0 = 0.f, qc1 = 0.f, qq0 = 0.f, qq1 = 0.f;
#pragma unroll 8
        for (int j = 0; j < 16; ++j) {
            f4 c = ci[j * 64 + lane];
            f4 q = qi[j * 64 + lane];
            qc0 += q[0]*c[0] + q[1]*c[1] + q[2]*c[2] + q[3]*c[3];
            qq0 += q[0]*q[0] + q[1]*q[1] + q[2]*q[2] + q[3]*q[3];
        }
#pragma unroll 8
        for (int j = 0; j < 16; ++j) {
            f4 c = ca[j * 64 + lane];
            f4 q = qa[j * 64 + lane];
            qc1 += q[0]*c[0] + q[1]*c[1] + q[2]*c[2] + q[3]*c[3];
            qq1 += q[0]*q[0] + q[1]*q[1] + q[2]*q[2] + q[3]*q[3];
        }
        float qc = qc0 + qc1;
        float qq = qq0 + qq1;
        float Q  = ch[0] + ch[1] + ch[2] + ch[3];

        // ---- wave-local butterfly reduce: every lane gets the full sums ----
#pragma unroll
        for (int off = 32; off > 0; off >>= 1) {
            qc += __shfl_xor(qc, off, 64);
            qq += __shfl_xor(qq, off, 64);
            Q  += __shfl_xor(Q,  off, 64);
        }
        const float h = (Q - qc) / qq;   // u/2, identical in all lanes

        // ---- pass 2: re-read (L2/L3-hot) + fused scale-add + store ----
        f4* oi = (f4*)(out + (size_t)b * HALF_N);
        f4* oa = (f4*)(out + (size_t)B * HALF_N + (size_t)b * HALF_N);
#pragma unroll 8
        for (int j = 0; j < 16; ++j) {
            f4 c = ci[j * 64 + lane];
            f4 q = qi[j * 64 + lane];
            oi[j * 64 + lane] = c + h * q;
        }
#pragma unroll 8
        for (int j = 0; j < 16; ++j) {
            f4 c = ca[j * 64 + lane];
            f4 q = qa[j * 64 + lane];
            oa[j * 64 + lane] = c + h * q;
        }
    }
}

extern "C" void kernel_launch(void* const* d_in, const int* in_sizes, int n_in,
                              void* d_out, int out_size, void* d_ws, size_t ws_size,
                              hipStream_t stream) {
    const float* c_iso   = (const float*)d_in[0];
    const float* c_aniso = (const float*)d_in[1];
    const float* q_iso   = (const float*)d_in[2];
    const float* q_aniso = (const float*)d_in[3];
    const float* charge  = (const float*)d_in[4];
    float* out = (float*)d_out;

    const int B = in_sizes[0] / HALF_N;   // 4096

    const int grid = (B + WPB * RPW - 1) / (WPB * RPW);   // 512
    qp_charge_norm_kernel<<<grid, BLOCK, 0, stream>>>(
        c_iso, c_aniso, q_iso, q_aniso, charge, out, B);
}

// Round 3
// 320.706 us; speedup vs baseline: 1.0594x; 1.0594x over previous
//
#include <hip/hip_runtime.h>

// QPChargeNormalization v4: per batch row b (n = 8192 = 4096 iso + 4096 aniso):
//   h = u/2 = (sum(charge[b]) - q.c) / (q.q);  x = c + h*q
//
// Evidence so far: the binding resource is the vector-memory path
// (~6.3 TB/s chip-wide). v1 saturated it (5.5 TB/s) but moved 1.6x the
// ideal bytes (epilogue re-read of c,q); v3 moved ideal HBM bytes but at
// only 8 waves/CU (4.7 TB/s path). v4 moves IDEAL path bytes (405 MB:
// each input byte through L1 exactly once, plus the write stream) at
// 24 waves/CU:
//   - one 512-thread block per row, grid = B = 4096
//   - dot pass: global->reg, accumulate q.c / q.q, and deterministically
//     stage q (32 KiB) + c_aniso (16 KiB) into LDS; c_iso stays in
//     registers (only 2 f4/thread -- too cheap for the allocator to sink)
//   - ONE __syncthreads; cross-wave combine via 24-float LDS partials
//   - epilogue: c from regs/LDS, q from LDS, plain f4 stores
//     (non-temporal stores measured +25% write amplification in v2: avoid)
// LDS 48.1 KiB/block -> 3 blocks/CU -> 24 waves/CU.

#define HALF_N 4096   // floats per row in each of the iso/aniso halves
#define BLOCK  512

typedef float f4 __attribute__((ext_vector_type(4)));

__device__ __forceinline__ float dot4(f4 a, f4 b) {
    return a[0]*b[0] + a[1]*b[1] + a[2]*b[2] + a[3]*b[3];
}

__global__ __launch_bounds__(BLOCK, 6) void qp_charge_norm_kernel(
    const float* __restrict__ c_iso,
    const float* __restrict__ c_aniso,
    const float* __restrict__ q_iso,
    const float* __restrict__ q_aniso,
    const float* __restrict__ charge,   // [B, 256]
    float* __restrict__ out,            // [B*4096 iso][B*4096 aniso]
    int B)
{
    const int b    = blockIdx.x;
    const int t    = threadIdx.x;
    const int wave = t >> 6;
    const int lane = t & 63;

    // 32 KiB q (iso 0..1023, aniso 1024..2047) + 16 KiB c_aniso + partials
    __shared__ f4    q_s[2048];
    __shared__ f4    ca_s[1024];
    __shared__ float part[24];

    const f4* ci = (const f4*)(c_iso   + (size_t)b * HALF_N);
    const f4* ca = (const f4*)(c_aniso + (size_t)b * HALF_N);
    const f4* qi = (const f4*)(q_iso   + (size_t)b * HALF_N);
    const f4* qa = (const f4*)(q_aniso + (size_t)b * HALF_N);

    // ---- single streaming pass: 8 coalesced f4 loads per thread ----
    f4 ci0 = ci[t];       f4 ci1 = ci[t + 512];
    f4 qi0 = qi[t];       f4 qi1 = qi[t + 512];
    f4 ca0 = ca[t];       f4 ca1 = ca[t + 512];
    f4 qa0 = qa[t];       f4 qa1 = qa[t + 512];

    float qc = dot4(qi0, ci0) + dot4(qi1, ci1) + dot4(qa0, ca0) + dot4(qa1, ca1);
    float qq = dot4(qi0, qi0) + dot4(qi1, qi1) + dot4(qa0, qa0) + dot4(qa1, qa1);

    // charge row: 256 floats, loaded by wave 0 as one f4 per lane
    float Q = 0.0f;
    if (wave == 0) {
        f4 ch = ((const f4*)(charge + (size_t)b * 256))[lane];
        Q = ch[0] + ch[1] + ch[2] + ch[3];
    }

    // deterministic staging: q and c_aniso live in LDS for the epilogue,
    // so the register allocator has nothing to sink to global re-reads.
    q_s[t]          = qi0;
    q_s[t + 512]    = qi1;
    q_s[1024 + t]   = qa0;
    q_s[1536 + t]   = qa1;
    ca_s[t]         = ca0;
    ca_s[t + 512]   = ca1;

    // ---- wave-local butterfly, then one cross-wave combine ----
#pragma unroll
    for (int off = 32; off > 0; off >>= 1) {
        qc += __shfl_xor(qc, off, 64);
        qq += __shfl_xor(qq, off, 64);
        Q  += __shfl_xor(Q,  off, 64);
    }
    if (lane == 0) {
        part[wave * 3 + 0] = qc;
        part[wave * 3 + 1] = qq;
        part[wave * 3 + 2] = Q;
    }
    __syncthreads();   // also covers the q_s/ca_s staging writes

    float tqc = 0.0f, tqq = 0.0f, tQ = 0.0f;
#pragma unroll
    for (int w = 0; w < 8; ++w) {   // broadcast reads, conflict-free
        tqc += part[w * 3 + 0];
        tqq += part[w * 3 + 1];
        tQ  += part[w * 3 + 2];
    }
    const float h = (tQ - tqc) / tqq;   // u/2

    // ---- epilogue: zero global re-reads ----
    f4* oi = (f4*)(out + (size_t)b * HALF_N);
    f4* oa = (f4*)(out + (size_t)B * HALF_N + (size_t)b * HALF_N);

    oi[t]       = ci0          + h * q_s[t];
    oi[t + 512] = ci1          + h * q_s[t + 512];
    oa[t]       = ca_s[t]      + h * q_s[1024 + t];
    oa[t + 512] = ca_s[t + 512] + h * q_s[1536 + t];
}

extern "C" void kernel_launch(void* const* d_in, const int* in_sizes, int n_in,
                              void* d_out, int out_size, void* d_ws, size_t ws_size,
                              hipStream_t stream) {
    const float* c_iso   = (const float*)d_in[0];
    const float* c_aniso = (const float*)d_in[1];
    const float* q_iso   = (const float*)d_in[2];
    const float* q_aniso = (const float*)d_in[3];
    const float* charge  = (const float*)d_in[4];
    float* out = (float*)d_out;

    const int B = in_sizes[0] / HALF_N;   // 4096

    qp_charge_norm_kernel<<<B, BLOCK, 0, stream>>>(
        c_iso, c_aniso, q_iso, q_aniso, charge, out, B);
}